// Round 7
// baseline (160.934 us; speedup 1.0000x reference)
//
#include <hip/hip_runtime.h>
#include <hip/hip_bf16.h>
#include <stdint.h>

// GAT layer: N=8192, F_IN=256, F_OUT=64, two branches (adj_in/adj_out), shared 'a'.

#define NN 8192
#define ALPHA 0.2f
#define L2E 1.44269504088896f
#define AL2E 0.288539008177792f   // 0.2 * log2(e)

typedef _Float16 f16;
typedef _Float16 f16x2 __attribute__((ext_vector_type(2)));
typedef _Float16 f16x4 __attribute__((ext_vector_type(4)));
typedef _Float16 f16x8 __attribute__((ext_vector_type(8)));
typedef float f32x4 __attribute__((ext_vector_type(4)));
typedef unsigned int u32;

// workspace layout (bytes). E1/E2 overlay WT (dead after k2).
#define WS_WT    0u         // f16 [128][256]
#define WS_E1    0u         // f16 [2][8192]
#define WS_E2    32768u     // f16 [2][8192]
#define WS_HT    65536u     // f16 [2][1024][64][8] blocked: HTB[b][j>>3][c][j&7]
#define WS_SRC   2162688u   // f32 [2][8192]
#define WS_DST   2228224u   // f32 [2][8192]
#define WS_DMAX  2293760u   // f32 [2]
#define WS_PACC  2294016u   // f32 [2][8192][64]

// non-temporal load (gfx940+ CPol: NT = bit 1) — adj is a 537MB single-use
// stream; NT avoids L3 (MALL) allocation on the miss path.
static __device__ __forceinline__ void gload16_nt(const void* g, void* l) {
    __builtin_amdgcn_global_load_lds(
        (const __attribute__((address_space(1))) void*)g,
        (__attribute__((address_space(3))) void*)l, 16, 0, 2);
}

// ---------------- kernel 1: WT[c][k] = W[k][c] as f16 ----------------
__global__ __launch_bounds__(256) void k1_wt(const float* __restrict__ Win,
                                             const float* __restrict__ Wout,
                                             f16* __restrict__ WT) {
    int c = blockIdx.x;
    int k = threadIdx.x;
    const float* W = (c < 64) ? Win : Wout;
    int cc = c & 63;
    WT[(size_t)c * 256 + k] = (f16)W[(size_t)k * 64 + cc];
}

// ---------------- kernel 2: h = x@W (MFMA), emit blocked HTB f16 + src/dst ----------------
__global__ __launch_bounds__(64) void k2_h(const float* __restrict__ x,
                                           const f16* __restrict__ WT,
                                           const float* __restrict__ a,
                                           f16* __restrict__ HT,
                                           float* __restrict__ srcw,
                                           float* __restrict__ dstw) {
    int l = threadIdx.x;
    int l15 = l & 15, lhi = l >> 4;
    int row0 = blockIdx.x * 16;

    f32x4 acc[8];
#pragma unroll
    for (int n = 0; n < 8; n++) { acc[n][0]=0.f; acc[n][1]=0.f; acc[n][2]=0.f; acc[n][3]=0.f; }

#pragma unroll
    for (int kc = 0; kc < 8; kc++) {
        int k = kc * 32 + lhi * 8;
        const float* xp = x + (size_t)(row0 + l15) * 256 + k;
        float4 xa = *(const float4*)xp;
        float4 xb = *(const float4*)(xp + 4);
        f16x8 af;
        af[0]=(f16)xa.x; af[1]=(f16)xa.y; af[2]=(f16)xa.z; af[3]=(f16)xa.w;
        af[4]=(f16)xb.x; af[5]=(f16)xb.y; af[6]=(f16)xb.z; af[7]=(f16)xb.w;
#pragma unroll
        for (int n = 0; n < 8; n++) {
            f16x8 bf = *(const f16x8*)(WT + (size_t)(16 * n + l15) * 256 + k);
            acc[n] = __builtin_amdgcn_mfma_f32_16x16x32_f16(af, bf, acc[n], 0, 0, 0);
        }
    }

    float as4[4], ad4[4];
#pragma unroll
    for (int nn = 0; nn < 4; nn++) {
        as4[nn] = a[16 * nn + l15];
        ad4[nn] = a[64 + 16 * nn + l15];
    }

    float s_in[4] = {0,0,0,0}, d_in[4] = {0,0,0,0};
    float s_out[4] = {0,0,0,0}, d_out[4] = {0,0,0,0};

#pragma unroll
    for (int n = 0; n < 8; n++) {
        int b = n >> 2;
        int ci = 16 * (n & 3) + l15;
        int jj = row0 + 4 * lhi;
        f16x4 hv;
#pragma unroll
        for (int q = 0; q < 4; q++) hv[q] = (f16)acc[n][q];
        *(f16x4*)(HT + (size_t)b * 524288 + (size_t)(jj >> 3) * 512 + (size_t)ci * 8 + (jj & 7)) = hv;
#pragma unroll
        for (int q = 0; q < 4; q++) {
            float v = acc[n][q];
            if (b == 0) { s_in[q]  += v * as4[n & 3]; d_in[q]  += v * ad4[n & 3]; }
            else        { s_out[q] += v * as4[n & 3]; d_out[q] += v * ad4[n & 3]; }
        }
    }

#pragma unroll
    for (int q = 0; q < 4; q++) {
#pragma unroll
        for (int m = 1; m < 16; m <<= 1) {
            s_in[q]  += __shfl_xor(s_in[q],  m, 64);
            d_in[q]  += __shfl_xor(d_in[q],  m, 64);
            s_out[q] += __shfl_xor(s_out[q], m, 64);
            d_out[q] += __shfl_xor(d_out[q], m, 64);
        }
    }
    if (l15 == 0) {
        int row = row0 + 4 * lhi;
#pragma unroll
        for (int q = 0; q < 4; q++) {
            srcw[row + q]        = s_in[q];
            srcw[8192 + row + q] = s_out[q];
            dstw[row + q]        = d_in[q];
            dstw[8192 + row + q] = d_out[q];
        }
    }
}

// ---------------- kernel 3: per-branch max of dst ----------------
__global__ __launch_bounds__(256) void k3_dmax(const float* __restrict__ dstw,
                                               float* __restrict__ dmax) {
    __shared__ float red[2][4];
    int t = threadIdx.x;
    int l = t & 63, w = t >> 6;
    for (int b = 0; b < 2; b++) {
        float v = -1e30f;
        for (int i = t; i < 8192; i += 256) v = fmaxf(v, dstw[b * 8192 + i]);
#pragma unroll
        for (int m = 1; m < 64; m <<= 1) v = fmaxf(v, __shfl_xor(v, m, 64));
        if (l == 0) red[b][w] = v;
    }
    __syncthreads();
    if (t == 0) dmax[0] = fmaxf(fmaxf(red[0][0], red[0][1]), fmaxf(red[0][2], red[0][3]));
    if (t == 1) dmax[1] = fmaxf(fmaxf(red[1][0], red[1][1]), fmaxf(red[1][2], red[1][3]));
}

// ---------------- kernel 3b: E tables, f16, normalized by dmax ----------------
__global__ __launch_bounds__(256) void k3b_e(const float* __restrict__ dstw,
                                             const float* __restrict__ dmax,
                                             f16* __restrict__ E1,
                                             f16* __restrict__ E2) {
    int i = blockIdx.x * 256 + threadIdx.x;
    int b = i >> 13;
    float d = dstw[i] - dmax[b];
    E1[i] = (f16)exp2f(d * L2E);
    E2[i] = (f16)exp2f(d * AL2E);
}

// ---------------- kernel 4: fused masked-softmax-attention ----------------
// Block = 8 waves (512 thr), 32 rows, one branch. j tiled by 256; wave wv owns
// the 32-j slice [tile*256 + wv*32) for BOTH row-groups (rows l15 and l15+16)
// -> each HT/E fragment feeds 2 row-groups (halves L2 traffic vs 16-row).
// adj staged NT via global_load_lds into a 3-deep LDS ring (96 KB), issued 2
// tiles ahead; iteration ends with counted s_waitcnt vmcnt(8) (stage t+2 stays
// in flight across the barrier — never drained in-loop).
__global__ __launch_bounds__(512, 2) void k4_main(const int* __restrict__ adj_in,
                                                  const int* __restrict__ adj_out,
                                                  const f16* __restrict__ HT,
                                                  const float* __restrict__ srcw,
                                                  const float* __restrict__ dmaxp,
                                                  const f16* __restrict__ E1g,
                                                  const f16* __restrict__ E2g,
                                                  float* __restrict__ pacc) {
    __shared__ __align__(16) char lds[98304];   // 3 x 32KB adj ring; epilogue reuses

    int t = threadIdx.x;
    int branch = blockIdx.x & 1;
    int row0 = (blockIdx.x >> 1) * 32;
    const int* adj = (branch ? adj_out : adj_in) + (size_t)row0 * NN;
    const f16* htg = HT + (size_t)branch * (64 * NN);
    const f16* e1b = E1g + branch * NN;
    const f16* e2b = E2g + branch * NN;

    int l = t & 63, wv = t >> 6;          // 8 waves
    int l15 = l & 15, lhi = l >> 4;
    int sw = l15 & 7;

    // per-row constants for the two row-groups: ev = max(k1*E1[j], k2*E2[j])
    float dmaxv = dmaxp[branch];
    f16x8 k1v0, k2v0, k1v1, k2v1;
    {
        float srcv = srcw[branch * NN + row0 + l15];
        float md = srcv + dmaxv;
        float mlog = fmaxf(md, ALPHA * md) * L2E;
        f16 k1 = (f16)exp2f(md * L2E - mlog);
        f16 k2 = (f16)exp2f(ALPHA * md * L2E - mlog);
#pragma unroll
        for (int i = 0; i < 8; i++) { k1v0[i] = k1; k2v0[i] = k2; }
    }
    {
        float srcv = srcw[branch * NN + row0 + 16 + l15];
        float md = srcv + dmaxv;
        float mlog = fmaxf(md, ALPHA * md) * L2E;
        f16 k1 = (f16)exp2f(md * L2E - mlog);
        f16 k2 = (f16)exp2f(ALPHA * md * L2E - mlog);
#pragma unroll
        for (int i = 0; i < 8; i++) { k1v1[i] = k1; k2v1[i] = k2; }
    }

    f32x4 acc0[4], acc1[4];
#pragma unroll
    for (int n = 0; n < 4; n++) {
        acc0[n][0]=0.f; acc0[n][1]=0.f; acc0[n][2]=0.f; acc0[n][3]=0.f;
        acc1[n][0]=0.f; acc1[n][1]=0.f; acc1[n][2]=0.f; acc1[n][3]=0.f;
    }
    float dn0 = 0.f, dn1 = 0.f;
    f16x2 one2; one2[0] = (f16)1.f; one2[1] = (f16)1.f;

    // stage one 256-j tile of 32 adj rows (32 KB): wave wv does rows wv*4..+3
    auto stage = [&](int tile, int buf) {
        const int* base = adj + tile * 256;
#pragma unroll
        for (int i = 0; i < 4; i++) {
            int r = wv * 4 + i;
            const int* src = base + (size_t)r * NN + ((l ^ (r & 7)) << 2);
            gload16_nt(src, lds + buf * 32768 + r * 1024);
        }
    };

    // prologue: stage 0 and 1; wait stage0 complete (leave stage1's 4 in flight... 8 total issued by this wave: 4+4; vmcnt counts per-wave)
    stage(0, 0);
    stage(1, 1);
    asm volatile("s_waitcnt vmcnt(4)");     // stage0's 4 done; stage1's 4 in flight
    __builtin_amdgcn_sched_barrier(0);
    __builtin_amdgcn_s_barrier();

    int js = wv * 32;
    int qb = (js >> 2) + 2 * lhi;           // 16B-chunk index within row

    for (int tile = 0; tile < 32; tile++) {
        int buf = tile - (tile / 3) * 3;    // tile % 3
        int nbuf = (buf == 2) ? 0 : buf + 1;
        int nnbuf = (nbuf == 2) ? 0 : nbuf + 1;
        (void)nbuf;

        // 1) E/HT register loads for this tile (L2-resident) — issued FIRST
        int jg = tile * 256 + js + lhi * 8;
        f16x8 e1v = *(const f16x8*)(e1b + jg);
        f16x8 e2v = *(const f16x8*)(e2b + jg);
        const f16* hb = htg + (size_t)(jg >> 3) * 512 + l15 * 8;
        f16x8 b0 = *(const f16x8*)(hb);
        f16x8 b1 = *(const f16x8*)(hb + 128);
        f16x8 b2 = *(const f16x8*)(hb + 256);
        f16x8 b3 = *(const f16x8*)(hb + 384);
        __builtin_amdgcn_sched_barrier(0);

        // 2) stage tile+2 (newest vmem -> compiler's E/HT waits leave these in flight)
        if (tile < 30) stage(tile + 2, nnbuf);
        __builtin_amdgcn_sched_barrier(0);

        // 3) adj masks from LDS, both row-groups
        const char* rowp0 = lds + buf * 32768 + l15 * 1024;
        const char* rowp1 = lds + buf * 32768 + (l15 + 16) * 1024;
        int4 a0 = *(const int4*)(rowp0 + (((qb    ) ^ sw) << 4));
        int4 a1 = *(const int4*)(rowp0 + (((qb + 1) ^ sw) << 4));
        int4 a2 = *(const int4*)(rowp1 + (((qb    ) ^ sw) << 4));
        int4 a3 = *(const int4*)(rowp1 + (((qb + 1) ^ sw) << 4));

        // 4) weights + MFMA, row-group 0
        {
            union { u32 u[4]; f16x8 h; } mu;
            mu.u[0] = (u32)(a0.x + (a0.y << 16)) * 0x3C00u;
            mu.u[1] = (u32)(a0.z + (a0.w << 16)) * 0x3C00u;
            mu.u[2] = (u32)(a1.x + (a1.y << 16)) * 0x3C00u;
            mu.u[3] = (u32)(a1.z + (a1.w << 16)) * 0x3C00u;
            f16x8 w = __builtin_elementwise_max(e1v * k1v0, e2v * k2v0) * mu.h;
            union { f16x8 h; f16x2 p[4]; } wu; wu.h = w;
#if __has_builtin(__builtin_amdgcn_fdot2)
            dn0 = __builtin_amdgcn_fdot2(wu.p[0], one2, dn0, false);
            dn0 = __builtin_amdgcn_fdot2(wu.p[1], one2, dn0, false);
            dn0 = __builtin_amdgcn_fdot2(wu.p[2], one2, dn0, false);
            dn0 = __builtin_amdgcn_fdot2(wu.p[3], one2, dn0, false);
#else
#pragma unroll
            for (int e = 0; e < 8; e++) dn0 += (float)w[e];
#endif
            acc0[0] = __builtin_amdgcn_mfma_f32_16x16x32_f16(w, b0, acc0[0], 0, 0, 0);
            acc0[1] = __builtin_amdgcn_mfma_f32_16x16x32_f16(w, b1, acc0[1], 0, 0, 0);
            acc0[2] = __builtin_amdgcn_mfma_f32_16x16x32_f16(w, b2, acc0[2], 0, 0, 0);
            acc0[3] = __builtin_amdgcn_mfma_f32_16x16x32_f16(w, b3, acc0[3], 0, 0, 0);
        }
        // 5) row-group 1 (same E/HT fragments)
        {
            union { u32 u[4]; f16x8 h; } mu;
            mu.u[0] = (u32)(a2.x + (a2.y << 16)) * 0x3C00u;
            mu.u[1] = (u32)(a2.z + (a2.w << 16)) * 0x3C00u;
            mu.u[2] = (u32)(a3.x + (a3.y << 16)) * 0x3C00u;
            mu.u[3] = (u32)(a3.z + (a3.w << 16)) * 0x3C00u;
            f16x8 w = __builtin_elementwise_max(e1v * k1v1, e2v * k2v1) * mu.h;
            union { f16x8 h; f16x2 p[4]; } wu; wu.h = w;
#if __has_builtin(__builtin_amdgcn_fdot2)
            dn1 = __builtin_amdgcn_fdot2(wu.p[0], one2, dn1, false);
            dn1 = __builtin_amdgcn_fdot2(wu.p[1], one2, dn1, false);
            dn1 = __builtin_amdgcn_fdot2(wu.p[2], one2, dn1, false);
            dn1 = __builtin_amdgcn_fdot2(wu.p[3], one2, dn1, false);
#else
#pragma unroll
            for (int e = 0; e < 8; e++) dn1 += (float)w[e];
#endif
            acc1[0] = __builtin_amdgcn_mfma_f32_16x16x32_f16(w, b0, acc1[0], 0, 0, 0);
            acc1[1] = __builtin_amdgcn_mfma_f32_16x16x32_f16(w, b1, acc1[1], 0, 0, 0);
            acc1[2] = __builtin_amdgcn_mfma_f32_16x16x32_f16(w, b2, acc1[2], 0, 0, 0);
            acc1[3] = __builtin_amdgcn_mfma_f32_16x16x32_f16(w, b3, acc1[3], 0, 0, 0);
        }

        // 6) counted wait: ensure stage(tile+1) done for next iter; stage(tile+2)
        //    (this wave's newest 4 loads) stays in flight across the barrier.
        asm volatile("s_waitcnt vmcnt(4)");
        __builtin_amdgcn_sched_barrier(0);
        __builtin_amdgcn_s_barrier();
    }

    // epilogue: reduce dn over lhi groups, merge 8 waves' partials in LDS
    dn0 += __shfl_xor(dn0, 16, 64); dn0 += __shfl_xor(dn0, 32, 64);
    dn1 += __shfl_xor(dn1, 16, 64); dn1 += __shfl_xor(dn1, 32, 64);
    __syncthreads();   // full drain; reuse ring LDS

    float* accL = (float*)lds;               // [8][32][64] = 64 KB
    float* dnp  = (float*)(lds + 65536);     // [8][32]
    if (lhi == 0) { dnp[wv * 32 + l15] = dn0; dnp[wv * 32 + 16 + l15] = dn1; }
#pragma unroll
    for (int n = 0; n < 4; n++)
#pragma unroll
        for (int q = 0; q < 4; q++) {
            accL[wv * 2048 + (4 * lhi + q) * 64 + 16 * n + l15]      = acc0[n][q];
            accL[wv * 2048 + (16 + 4 * lhi + q) * 64 + 16 * n + l15] = acc1[n][q];
        }
    __syncthreads();

    int r = t >> 4;              // 0..31
    int c4 = (t & 15) * 4;
    float dsum = 0.f;
#pragma unroll
    for (int w8 = 0; w8 < 8; w8++) dsum += dnp[w8 * 32 + r];
    float inv = 1.0f / dsum;
    float4 o;
#pragma unroll
    for (int cc = 0; cc < 4; cc++) {
        int idx = r * 64 + c4 + cc;
        float s = 0.f;
#pragma unroll
        for (int w8 = 0; w8 < 8; w8++) s += accL[w8 * 2048 + idx];
        ((float*)&o)[cc] = s * inv;
    }
    *(float4*)(pacc + (size_t)branch * 524288 + (size_t)(row0 + r) * 64 + c4) = o;
}

// ---------------- kernel 5: combine branches + ELU ----------------
__global__ __launch_bounds__(256) void k5_combine(const float* __restrict__ pacc,
                                                  float* __restrict__ out) {
    size_t idx = (size_t)blockIdx.x * 256 + threadIdx.x;
    float4 p0 = *(const float4*)(pacc + idx * 4);
    float4 p1 = *(const float4*)(pacc + 524288 + idx * 4);
    float4 o;
    float v;
    v = 0.5f * (p0.x + p1.x); o.x = (v > 0.f) ? v : (exp2f(v * L2E) - 1.f);
    v = 0.5f * (p0.y + p1.y); o.y = (v > 0.f) ? v : (exp2f(v * L2E) - 1.f);
    v = 0.5f * (p0.z + p1.z); o.z = (v > 0.f) ? v : (exp2f(v * L2E) - 1.f);
    v = 0.5f * (p0.w + p1.w); o.w = (v > 0.f) ? v : (exp2f(v * L2E) - 1.f);
    *(float4*)(out + idx * 4) = o;
}

extern "C" void kernel_launch(void* const* d_in, const int* in_sizes, int n_in,
                              void* d_out, int out_size, void* d_ws, size_t ws_size,
                              hipStream_t stream) {
    const float* x       = (const float*)d_in[0];
    const int*   adj_in  = (const int*)d_in[1];
    const int*   adj_out = (const int*)d_in[2];
    const float* W_in    = (const float*)d_in[3];
    const float* W_out   = (const float*)d_in[4];
    const float* a       = (const float*)d_in[5];
    float* out = (float*)d_out;

    char* ws = (char*)d_ws;
    f16*   WT   = (f16*)(ws + WS_WT);
    f16*   E1   = (f16*)(ws + WS_E1);
    f16*   E2   = (f16*)(ws + WS_E2);
    f16*   HT   = (f16*)(ws + WS_HT);
    float* srcw = (float*)(ws + WS_SRC);
    float* dstw = (float*)(ws + WS_DST);
    float* dmax = (float*)(ws + WS_DMAX);
    float* pacc = (float*)(ws + WS_PACC);
    // requires ws_size >= ~6.2 MB

    hipLaunchKernelGGL(k1_wt,     dim3(128),  dim3(256), 0, stream, W_in, W_out, WT);
    hipLaunchKernelGGL(k2_h,      dim3(512),  dim3(64),  0, stream, x, WT, a, HT, srcw, dstw);
    hipLaunchKernelGGL(k3_dmax,   dim3(1),    dim3(256), 0, stream, dstw, dmax);
    hipLaunchKernelGGL(k3b_e,     dim3(64),   dim3(256), 0, stream, dstw, dmax, E1, E2);
    hipLaunchKernelGGL(k4_main,   dim3(512),  dim3(512), 0, stream, adj_in, adj_out, HT, srcw, dmax, E1, E2, pacc);
    hipLaunchKernelGGL(k5_combine,dim3(512),  dim3(256), 0, stream, pacc, out);
}